// Round 1
// baseline (19259.393 us; speedup 1.0000x reference)
//
#include <hip/hip_runtime.h>
#include <math.h>

namespace {
constexpr int BATCH = 4096;
constexpr int DEPTH_ = 7;
constexpr int NN   = 127;   // 2^7 - 1 nodes
constexpr int IDIM = 300;
constexpr int HD   = 150;
constexpr int K3   = 450;   // 3*HD
constexpr int ROWS = 16;    // rows (b,s) per block
constexpr int NT   = 256;   // threads per block
constexpr int KT   = 50;    // K chunk staged in LDS
constexpr int CT   = 128;   // phase-A column tile (4 tiles cover 512 >= 450)
constexpr int WSTR = 132;   // weight-tile LDS stride (16B-aligned float4 reads)
constexpr int XSTR = 304;   // xs stride
constexpr int CHSTR = 152;  // chs/hts/fg stride

constexpr int LDS_XS  = ROWS * XSTR;        // 4864 floats (aliased by fg: 32*152=4864)
constexpr int LDS_WS  = KT * WSTR;          // 6600
constexpr int LDS_IUO = ROWS * K3;          // 7200
constexpr int LDS_HTS = ROWS * CHSTR;       // 2432
constexpr int LDS_CHS = 2 * ROWS * CHSTR;   // 4864
constexpr int LDS_LEAF_FLOATS = LDS_XS + LDS_WS + LDS_IUO;                  // 18664 -> 74,656 B
constexpr int LDS_INT_FLOATS  = LDS_LEAF_FLOATS + LDS_HTS + LDS_CHS;        // 25,960 -> 103,840 B

__device__ __forceinline__ float sigmoidf_(float v) {
    return 1.0f / (1.0f + __expf(-v));
}
} // namespace

// One kernel per tree level. Computes, for ROWS (batch,node) rows:
//   iuo = x_row @ Wiuo^T (+ h_tilda @ Uiuo^T if internal) + biuo
//   f   = sigmoid(ch @ Uf_w^T + Uf_b)            (internal only)
//   c_new = sig(i)*tanh(u) + sum_k f_k*cc_k ;  h_new = sig(o)*tanh(c_new)
template<bool INTERNAL>
__global__ __launch_bounds__(NT)
void tree_level_kernel(const float* __restrict__ x,
                       const float* __restrict__ Wiuo,
                       const float* __restrict__ Uiuo,
                       const float* __restrict__ biuo,
                       const float* __restrict__ Uf_w,
                       const float* __restrict__ Uf_b,
                       float* __restrict__ h_all,   // d_out  [B][127][150]
                       float* __restrict__ c_all,   // d_ws   [B][127][150]
                       int start, int sizeLog2, int cstart)
{
    extern __shared__ float lds[];
    float* xs  = lds;                 // [16][304]
    float* ws  = lds + LDS_XS;        // [50][132]
    float* iuo = ws + LDS_WS;         // [16][450]
    float* hts = iuo + LDS_IUO;       // [16][152]  (internal)
    float* chs = hts + LDS_HTS;       // [32][152]  (internal) row = c*16+lr
    float* fg  = xs;                  // alias: [32][152] after phase A

    const int t    = threadIdx.x;
    const int size = 1 << sizeLog2;
    const int row0 = blockIdx.x * ROWS;

    // ---- stage x rows (coalesced global, stride-1 LDS writes) ----
    for (int idx = t; idx < ROWS * IDIM; idx += NT) {
        int lr = idx / IDIM;
        int i  = idx - lr * IDIM;
        int row = row0 + lr;
        int b = row >> sizeLog2;
        int s = row & (size - 1);
        xs[lr * XSTR + i] = x[((size_t)b * NN + start + s) * IDIM + i];
    }
    if (INTERNAL) {
        // children h: row rc = c*16+lr
        for (int idx = t; idx < 2 * ROWS * HD; idx += NT) {
            int rc = idx / HD;
            int g  = idx - rc * HD;
            int lr = rc & (ROWS - 1);
            int c  = rc >> 4;
            int row = row0 + lr;
            int b = row >> sizeLog2;
            int s = row & (size - 1);
            chs[rc * CHSTR + g] = h_all[((size_t)b * NN + cstart + 2 * s + c) * HD + g];
        }
        __syncthreads();
        for (int idx = t; idx < ROWS * HD; idx += NT) {
            int lr = idx / HD;
            int g  = idx - lr * HD;
            hts[lr * CHSTR + g] = chs[lr * CHSTR + g] + chs[(ROWS + lr) * CHSTR + g];
        }
    }

    // ---- phase A: iuo[16][450] ----
    const int rg = t >> 5;           // 0..7  -> rows 2*rg, 2*rg+1
    const int cg = t & 31;           // 0..31 -> cols 4*cg .. 4*cg+3 within tile
    const int r0 = 2 * rg, r1 = r0 + 1;

    for (int j = 0; j < 4; ++j) {
        const int colbase = j * CT;
        float acc[2][4] = {{0.f,0.f,0.f,0.f},{0.f,0.f,0.f,0.f}};

        // x @ Wiuo^T, K=300 in chunks of 50
        for (int kb = 0; kb < IDIM; kb += KT) {
            __syncthreads();   // previous ws consumers done
            for (int idx = t; idx < CT * KT; idx += NT) {
                int cc = idx / KT;
                int ii = idx - cc * KT;
                int k  = colbase + cc;
                ws[ii * WSTR + cc] = (k < K3) ? Wiuo[(size_t)k * IDIM + kb + ii] : 0.0f;
            }
            __syncthreads();
            for (int ii = 0; ii < KT; ++ii) {
                float a0 = xs[r0 * XSTR + kb + ii];
                float a1 = xs[r1 * XSTR + kb + ii];
                float4 w = *(const float4*)&ws[ii * WSTR + 4 * cg];
                acc[0][0] = fmaf(a0, w.x, acc[0][0]);
                acc[0][1] = fmaf(a0, w.y, acc[0][1]);
                acc[0][2] = fmaf(a0, w.z, acc[0][2]);
                acc[0][3] = fmaf(a0, w.w, acc[0][3]);
                acc[1][0] = fmaf(a1, w.x, acc[1][0]);
                acc[1][1] = fmaf(a1, w.y, acc[1][1]);
                acc[1][2] = fmaf(a1, w.z, acc[1][2]);
                acc[1][3] = fmaf(a1, w.w, acc[1][3]);
            }
        }
        if (INTERNAL) {
            // h_tilda @ Uiuo^T, K=150 in chunks of 50
            for (int kb = 0; kb < HD; kb += KT) {
                __syncthreads();
                for (int idx = t; idx < CT * KT; idx += NT) {
                    int cc = idx / KT;
                    int ii = idx - cc * KT;
                    int k  = colbase + cc;
                    ws[ii * WSTR + cc] = (k < K3) ? Uiuo[(size_t)k * HD + kb + ii] : 0.0f;
                }
                __syncthreads();
                for (int ii = 0; ii < KT; ++ii) {
                    float a0 = hts[r0 * CHSTR + kb + ii];
                    float a1 = hts[r1 * CHSTR + kb + ii];
                    float4 w = *(const float4*)&ws[ii * WSTR + 4 * cg];
                    acc[0][0] = fmaf(a0, w.x, acc[0][0]);
                    acc[0][1] = fmaf(a0, w.y, acc[0][1]);
                    acc[0][2] = fmaf(a0, w.z, acc[0][2]);
                    acc[0][3] = fmaf(a0, w.w, acc[0][3]);
                    acc[1][0] = fmaf(a1, w.x, acc[1][0]);
                    acc[1][1] = fmaf(a1, w.y, acc[1][1]);
                    acc[1][2] = fmaf(a1, w.z, acc[1][2]);
                    acc[1][3] = fmaf(a1, w.w, acc[1][3]);
                }
            }
        }
        for (int q = 0; q < 4; ++q) {
            int k = colbase + 4 * cg + q;
            if (k < K3) {
                float bv = biuo[k];
                iuo[r0 * K3 + k] = acc[0][q] + bv;
                iuo[r1 * K3 + k] = acc[1][q] + bv;
            }
        }
    }

    // ---- phase B (internal): f = sigmoid(ch @ Uf_w^T + Uf_b) -> fg[32][152] ----
    if (INTERNAL) {
        const int rg2 = t >> 4;      // 0..15 -> child-rows 2*rg2, 2*rg2+1
        const int cg2 = t & 15;      // 0..15 -> cols 4*cg2..+3 within 64-col tile
        const int rr0 = 2 * rg2, rr1 = rr0 + 1;
        for (int j2 = 0; j2 < 3; ++j2) {   // 3 tiles of 64 cover 192 >= 150
            const int colbase = j2 * 64;
            float acc[2][4] = {{0.f,0.f,0.f,0.f},{0.f,0.f,0.f,0.f}};
            for (int kb = 0; kb < HD; kb += KT) {
                __syncthreads();   // also orders last phase-A xs reads before fg writes
                for (int idx = t; idx < 64 * KT; idx += NT) {
                    int cc = idx / KT;
                    int ii = idx - cc * KT;
                    int k  = colbase + cc;
                    ws[ii * WSTR + cc] = (k < HD) ? Uf_w[(size_t)k * HD + kb + ii] : 0.0f;
                }
                __syncthreads();
                for (int ii = 0; ii < KT; ++ii) {
                    float a0 = chs[rr0 * CHSTR + kb + ii];
                    float a1 = chs[rr1 * CHSTR + kb + ii];
                    float4 w = *(const float4*)&ws[ii * WSTR + 4 * cg2];
                    acc[0][0] = fmaf(a0, w.x, acc[0][0]);
                    acc[0][1] = fmaf(a0, w.y, acc[0][1]);
                    acc[0][2] = fmaf(a0, w.z, acc[0][2]);
                    acc[0][3] = fmaf(a0, w.w, acc[0][3]);
                    acc[1][0] = fmaf(a1, w.x, acc[1][0]);
                    acc[1][1] = fmaf(a1, w.y, acc[1][1]);
                    acc[1][2] = fmaf(a1, w.z, acc[1][2]);
                    acc[1][3] = fmaf(a1, w.w, acc[1][3]);
                }
            }
            for (int q = 0; q < 4; ++q) {
                int k = colbase + 4 * cg2 + q;
                if (k < HD) {
                    float bv = Uf_b[k];
                    fg[rr0 * CHSTR + k] = sigmoidf_(acc[0][q] + bv);
                    fg[rr1 * CHSTR + k] = sigmoidf_(acc[1][q] + bv);
                }
            }
        }
    }
    __syncthreads();

    // ---- phase C: gates, write h (d_out) and c (ws) ----
    for (int idx = t; idx < ROWS * HD; idx += NT) {
        int lr = idx / HD;
        int g  = idx - lr * HD;
        int row = row0 + lr;
        int b = row >> sizeLog2;
        int s = row & (size - 1);

        float ig = iuo[lr * K3 + g];
        float ug = iuo[lr * K3 + HD + g];
        float og = iuo[lr * K3 + 2 * HD + g];

        float csum = 0.0f;
        if (INTERNAL) {
            size_t ci = ((size_t)b * NN + cstart + 2 * s) * HD + g;
            float cc0 = c_all[ci];
            float cc1 = c_all[ci + HD];
            float f0 = fg[lr * CHSTR + g];
            float f1 = fg[(ROWS + lr) * CHSTR + g];
            csum = f0 * cc0 + f1 * cc1;
        }
        float cn = sigmoidf_(ig) * tanhf(ug) + csum;
        float hn = sigmoidf_(og) * tanhf(cn);
        size_t oi = ((size_t)b * NN + start + s) * HD + g;
        h_all[oi] = hn;
        c_all[oi] = cn;
    }
}

extern "C" void kernel_launch(void* const* d_in, const int* in_sizes, int n_in,
                              void* d_out, int out_size, void* d_ws, size_t ws_size,
                              hipStream_t stream) {
    const float* x    = (const float*)d_in[0];
    const float* Wiuo = (const float*)d_in[1];
    const float* Uiuo = (const float*)d_in[2];
    const float* biuo = (const float*)d_in[3];
    const float* Ufw  = (const float*)d_in[4];
    const float* Ufb  = (const float*)d_in[5];
    float* h = (float*)d_out;
    float* c = (float*)d_ws;   // 4096*127*150*4 = 312 MB of scratch for cell state

    (void)hipFuncSetAttribute((const void*)tree_level_kernel<false>,
                              hipFuncAttributeMaxDynamicSharedMemorySize, 160 * 1024);
    (void)hipFuncSetAttribute((const void*)tree_level_kernel<true>,
                              hipFuncAttributeMaxDynamicSharedMemorySize, 160 * 1024);

    for (int d = DEPTH_ - 1; d >= 0; --d) {
        const int size   = 1 << d;
        const int start  = size - 1;
        const int cstart = 2 * size - 1;
        const int blocks = (BATCH * size) / ROWS;
        if (d == DEPTH_ - 1) {
            tree_level_kernel<false><<<blocks, NT, LDS_LEAF_FLOATS * sizeof(float), stream>>>(
                x, Wiuo, Uiuo, biuo, Ufw, Ufb, h, c, start, d, cstart);
        } else {
            tree_level_kernel<true><<<blocks, NT, LDS_INT_FLOATS * sizeof(float), stream>>>(
                x, Wiuo, Uiuo, biuo, Ufw, Ufb, h, c, start, d, cstart);
        }
    }
}

// Round 3
// 2422.008 us; speedup vs baseline: 7.9518x; 7.9518x over previous
//
#include <hip/hip_runtime.h>

typedef float  f32x4  __attribute__((ext_vector_type(4)));
typedef short  s16x8  __attribute__((ext_vector_type(8)));
typedef short  s16x4  __attribute__((ext_vector_type(4)));
typedef __bf16 bf16x8 __attribute__((ext_vector_type(8)));

namespace {
constexpr int BATCH = 4096;
constexpr int DEPTH_ = 7;
constexpr int NN   = 127;
constexpr int IDIM = 300;
constexpr int HD   = 150;
constexpr int ROWS = 32;    // parent rows per block
constexpr int NT   = 320;   // 5 waves; wave w owns col-triples {2w, 2w+1} of 10
constexpr int XSTR = 328;   // xs stride (shorts): 164 dwords, 164%8=4 -> uniform banks
constexpr int CSTR = 168;   // chs/fg stride (shorts): 84 dwords, 84%8=4 -> uniform banks

constexpr int XS_SH = ROWS * XSTR;       // 10496 shorts
constexpr int CH_SH = 2 * ROWS * CSTR;   // 10752 shorts
constexpr int FG_SH = 2 * ROWS * CSTR;   // 10752 shorts (aliases xs; FG_SH >= XS_SH)
constexpr int LDS_LEAF_B = XS_SH * 2;             // 20992 B
constexpr int LDS_INT_B  = (CH_SH + FG_SH) * 2;   // 43008 B

__device__ __forceinline__ short f2bf(float f) {
    union { __bf16 b; short s; } u; u.b = (__bf16)f; return u.s;
}
__device__ __forceinline__ float bf2f(short s) {
    union { float f; unsigned u; } v; v.u = ((unsigned)(unsigned short)s) << 16; return v.f;
}
__device__ __forceinline__ float sig_(float x)  { return 1.0f / (1.0f + __expf(-x)); }
__device__ __forceinline__ float tanh_(float x) { float e = __expf(2.0f * x); return 1.0f - 2.0f / (e + 1.0f); }

__device__ __forceinline__ s16x8 cvt8(float a0,float a1,float a2,float a3,
                                      float a4,float a5,float a6,float a7) {
    union { bf16x8 b; s16x8 s; } u;
    u.b = bf16x8{(__bf16)a0,(__bf16)a1,(__bf16)a2,(__bf16)a3,
                 (__bf16)a4,(__bf16)a5,(__bf16)a6,(__bf16)a7};
    return u.s;
}

// B fragment: 8 consecutive fp32 at p -> bf16, but only the first n are real;
// elements j >= n are zeroed (they pair with zero-padded A slots).
// n >= 8: full vector path. n <= 0: zero fragment (no dereference).
__device__ __forceinline__ s16x8 ldfragN(const float* p, int n, bool valid) {
    if (!valid || n <= 0) return s16x8{0,0,0,0,0,0,0,0};
    if (n >= 8) {
        float2 w0 = *(const float2*)(p + 0);
        float2 w1 = *(const float2*)(p + 2);
        float2 w2 = *(const float2*)(p + 4);
        float2 w3 = *(const float2*)(p + 6);
        return cvt8(w0.x,w0.y,w1.x,w1.y,w2.x,w2.y,w3.x,w3.y);
    }
    union { bf16x8 b; s16x8 s; } u;
    u.s = s16x8{0,0,0,0,0,0,0,0};
    #pragma unroll
    for (int j = 0; j < 8; ++j)
        if (j < n) u.b[j] = (__bf16)p[j];
    return u.s;
}

__device__ __forceinline__ f32x4 MFMA(s16x8 a, s16x8 b, f32x4 c) {
    return __builtin_amdgcn_mfma_f32_16x16x32_bf16(a, b, c, 0, 0, 0);
}
} // namespace

// D = A*B + C lane maps (gfx950 16x16x32 bf16):
//   A frag: row = lane&15, 8 k-slots per lane; B frag: col = lane&15, same k-slots.
//   (A and B share the lane->k map, so any consistent contiguous assumption is
//    correct up to a harmless K-permutation.)
//   C/D   : col = lane&15, row = 4*(lane>>4)+reg   [verified m89/m91]
template<bool INTERNAL>
__global__ __launch_bounds__(NT)
void lvl_kernel(const float* __restrict__ x, const float* __restrict__ Wiuo,
                const float* __restrict__ Uiuo, const float* __restrict__ biuo,
                const float* __restrict__ Ufw, const float* __restrict__ Ufb,
                float* __restrict__ h_all, float* __restrict__ c_all,
                int start, int lg, int cstart)
{
    extern __shared__ short smem[];
    short* chs = smem;                              // [64][CSTR] bf16 children h (internal)
    short* xs  = INTERNAL ? (smem + CH_SH) : smem;  // [32][XSTR] bf16 x rows
    short* fg  = xs;                                // alias after phase A: [64][CSTR] f-gates

    const int t    = threadIdx.x;
    const int wv   = t >> 6;        // 0..4
    const int ln   = t & 63;
    const int l15  = ln & 15;
    const int kg   = ln >> 4;       // 0..3
    const int row0 = blockIdx.x * ROWS;
    const int size = 1 << lg;

    // ---------------- stage x (fp32 -> bf16 LDS, zero-padded to XSTR) ----------------
    {
        constexpr int NQ = XSTR / 4;    // 82 quads/row
        for (int q = t; q < ROWS * NQ; q += NT) {
            int lr = q / NQ, i0 = (q - lr * NQ) * 4;
            int row = row0 + lr, b = row >> lg, s = row & (size - 1);
            s16x4 v = {0,0,0,0};
            if (i0 < IDIM) {   // IDIM%4==0: full quads only
                const float4 f = *(const float4*)(x + ((size_t)b*NN + start + s)*IDIM + i0);
                v = s16x4{ f2bf(f.x), f2bf(f.y), f2bf(f.z), f2bf(f.w) };
            }
            *(s16x4*)&xs[lr * XSTR + i0] = v;
        }
    }
    // ---------------- stage children h (internal, zero-padded to CSTR) ----------------
    if (INTERNAL) {
        constexpr int NQ = CSTR / 4;    // 42 quads/row
        for (int q = t; q < 2 * ROWS * NQ; q += NT) {
            int cl = q / NQ, i0 = (q - cl * NQ) * 4;
            int lr = cl >> 1, cc = cl & 1;              // child row cl = 2*parent + cc
            int row = row0 + lr, b = row >> lg, s = row & (size - 1);
            const float* hp = h_all + ((size_t)b*NN + cstart + 2*s + cc) * HD;
            s16x4 v = {0,0,0,0};
            if (i0 + 3 < HD) {
                float2 f0 = *(const float2*)(hp + i0);
                float2 f1 = *(const float2*)(hp + i0 + 2);
                v = s16x4{ f2bf(f0.x), f2bf(f0.y), f2bf(f1.x), f2bf(f1.y) };
            } else if (i0 < HD) {       // i0 == 148
                float2 f0 = *(const float2*)(hp + i0);
                v = s16x4{ f2bf(f0.x), f2bf(f0.y), 0, 0 };
            }
            *(s16x4*)&chs[cl * CSTR + i0] = v;
        }
    }
    __syncthreads();

    // ---------------- phase A: iuo accumulators ----------------
    // wave wv owns in-gate col tiles (triples) {2wv, 2wv+1}; cols padded per-gate to 160
    f32x4 acc[2][2][3] = {};            // [row-tile mt][triple tt][gate g]
    int  cix[2]; bool bval[2];
    const float* wb[2][3];
    #pragma unroll
    for (int tt = 0; tt < 2; ++tt) {
        int cc = 16 * (2*wv + tt) + l15;
        cix[tt] = cc; bval[tt] = (cc < HD);
        int ccc = bval[tt] ? cc : 0;
        #pragma unroll
        for (int g = 0; g < 3; ++g)
            wb[tt][g] = Wiuo + (size_t)(g*HD + ccc) * IDIM;
    }

    #pragma unroll
    for (int kb = 0; kb < 320; kb += 32) {          // K=300 padded to 320 (A zero-padded)
        int ka = kb + 8 * kg;
        s16x8 a0 = *(const s16x8*)&xs[( l15      ) * XSTR + ka];
        s16x8 a1 = *(const s16x8*)&xs[( 16 + l15 ) * XSTR + ka];
        #pragma unroll
        for (int tt = 0; tt < 2; ++tt)
            #pragma unroll
            for (int g = 0; g < 3; ++g) {
                s16x8 bf = ldfragN(wb[tt][g] + ka, IDIM - ka, bval[tt]);
                acc[0][tt][g] = MFMA(a0, bf, acc[0][tt][g]);
                acc[1][tt][g] = MFMA(a1, bf, acc[1][tt][g]);
            }
    }

    if (INTERNAL) {
        // + h_tilda @ Uiuo^T, h_tilda built on the fly from chs pairs
        const float* ub[2][3];
        #pragma unroll
        for (int tt = 0; tt < 2; ++tt) {
            int ccc = bval[tt] ? cix[tt] : 0;
            #pragma unroll
            for (int g = 0; g < 3; ++g)
                ub[tt][g] = Uiuo + (size_t)(g*HD + ccc) * HD;
        }
        #pragma unroll
        for (int kb = 0; kb < 160; kb += 32) {      // K=150 padded to 160
            int ka = kb + 8 * kg;
            s16x8 hs[2];
            #pragma unroll
            for (int mt = 0; mt < 2; ++mt) {
                int pr = 16 * mt + l15;
                s16x8 h0 = *(const s16x8*)&chs[(2*pr    ) * CSTR + ka];
                s16x8 h1 = *(const s16x8*)&chs[(2*pr + 1) * CSTR + ka];
                union { bf16x8 b; s16x8 s; } u0, u1, uo;
                u0.s = h0; u1.s = h1;
                #pragma unroll
                for (int e = 0; e < 8; ++e)
                    uo.b[e] = (__bf16)((float)u0.b[e] + (float)u1.b[e]);
                hs[mt] = uo.s;
            }
            #pragma unroll
            for (int tt = 0; tt < 2; ++tt)
                #pragma unroll
                for (int g = 0; g < 3; ++g) {
                    s16x8 bf = ldfragN(ub[tt][g] + ka, HD - ka, bval[tt]);
                    acc[0][tt][g] = MFMA(hs[0], bf, acc[0][tt][g]);
                    acc[1][tt][g] = MFMA(hs[1], bf, acc[1][tt][g]);
                }
        }

        // ---------------- f-gate GEMM: f = sigmoid(ch @ Ufw^T + Ufb) ----------------
        f32x4 facc[4][2] = {};          // [child row-tile][col-tile]
        int  fcix[2]; bool fv[2];
        const float* fb[2];
        #pragma unroll
        for (int ct = 0; ct < 2; ++ct) {
            int fc = 16 * (2*wv + ct) + l15;
            fcix[ct] = fc; fv[ct] = (fc < HD);
            fb[ct] = Ufw + (size_t)(fv[ct] ? fc : 0) * HD;
        }
        #pragma unroll
        for (int kb = 0; kb < 160; kb += 32) {
            int ka = kb + 8 * kg;
            s16x8 af[4];
            #pragma unroll
            for (int rt = 0; rt < 4; ++rt)
                af[rt] = *(const s16x8*)&chs[(16*rt + l15) * CSTR + ka];
            #pragma unroll
            for (int ct = 0; ct < 2; ++ct) {
                s16x8 bf = ldfragN(fb[ct] + ka, HD - ka, fv[ct]);
                #pragma unroll
                for (int rt = 0; rt < 4; ++rt)
                    facc[rt][ct] = MFMA(af[rt], bf, facc[rt][ct]);
            }
        }
        __syncthreads();    // xs dead everywhere -> reuse as fg
        #pragma unroll
        for (int ct = 0; ct < 2; ++ct) {
            if (fcix[ct] < HD) {
                float fbias = Ufb[fcix[ct]];
                #pragma unroll
                for (int rt = 0; rt < 4; ++rt)
                    #pragma unroll
                    for (int r = 0; r < 4; ++r) {
                        int crow = 16*rt + 4*kg + r;
                        fg[crow * CSTR + fcix[ct]] = f2bf(sig_(facc[rt][ct][r] + fbias));
                    }
            }
        }
        __syncthreads();
    }

    // ---------------- epilogue: gates, csum, write h & c ----------------
    #pragma unroll
    for (int tt = 0; tt < 2; ++tt) {
        int c = cix[tt];
        if (c >= HD) continue;
        float bi = biuo[c], bu = biuo[HD + c], bo = biuo[2*HD + c];
        #pragma unroll
        for (int mt = 0; mt < 2; ++mt)
            #pragma unroll
            for (int r = 0; r < 4; ++r) {
                int pl = 16*mt + 4*kg + r;
                int row = row0 + pl, b = row >> lg, s = row & (size - 1);
                float ig = acc[mt][tt][0][r] + bi;
                float ug = acc[mt][tt][1][r] + bu;
                float og = acc[mt][tt][2][r] + bo;
                float csum = 0.0f;
                if (INTERNAL) {
                    int cl = 2 * pl;
                    float f0 = bf2f(fg[(cl    ) * CSTR + c]);
                    float f1 = bf2f(fg[(cl + 1) * CSTR + c]);
                    const float* cp = c_all + ((size_t)b*NN + cstart + 2*s) * HD + c;
                    csum = f0 * cp[0] + f1 * cp[HD];
                }
                float cn = sig_(ig) * tanh_(ug) + csum;
                float hn = sig_(og) * tanh_(cn);
                size_t oi = ((size_t)b*NN + start + s) * HD + c;
                h_all[oi] = hn;
                c_all[oi] = cn;
            }
    }
}

extern "C" void kernel_launch(void* const* d_in, const int* in_sizes, int n_in,
                              void* d_out, int out_size, void* d_ws, size_t ws_size,
                              hipStream_t stream) {
    const float* x    = (const float*)d_in[0];
    const float* Wiuo = (const float*)d_in[1];
    const float* Uiuo = (const float*)d_in[2];
    const float* biuo = (const float*)d_in[3];
    const float* Ufw  = (const float*)d_in[4];
    const float* Ufb  = (const float*)d_in[5];
    float* h = (float*)d_out;
    float* c = (float*)d_ws;    // 312 MB cell-state scratch

    (void)hipFuncSetAttribute((const void*)lvl_kernel<false>,
                              hipFuncAttributeMaxDynamicSharedMemorySize, 64 * 1024);
    (void)hipFuncSetAttribute((const void*)lvl_kernel<true>,
                              hipFuncAttributeMaxDynamicSharedMemorySize, 64 * 1024);

    for (int d = DEPTH_ - 1; d >= 0; --d) {
        const int size   = 1 << d;
        const int start  = size - 1;
        const int cstart = 2 * size - 1;
        const int blocks = (BATCH * size) / ROWS;
        if (d == DEPTH_ - 1) {
            lvl_kernel<false><<<blocks, NT, LDS_LEAF_B, stream>>>(
                x, Wiuo, Uiuo, biuo, Ufw, Ufb, h, c, start, d, cstart);
        } else {
            lvl_kernel<true><<<blocks, NT, LDS_INT_B, stream>>>(
                x, Wiuo, Uiuo, biuo, Ufw, Ufb, h, c, start, d, cstart);
        }
    }
}

// Round 4
// 1566.869 us; speedup vs baseline: 12.2916x; 1.5458x over previous
//
#include <hip/hip_runtime.h>

typedef float  f32x4  __attribute__((ext_vector_type(4)));
typedef short  s16x8  __attribute__((ext_vector_type(8)));
typedef short  s16x4  __attribute__((ext_vector_type(4)));
typedef __bf16 bf16x8 __attribute__((ext_vector_type(8)));

namespace {
constexpr int BATCH = 4096;
constexpr int DEPTH_ = 7;
constexpr int NN   = 127;
constexpr int CN   = 126;   // c scratch: nodes 1..126 (root c never read)
constexpr int IDIM = 300;
constexpr int HD   = 150;
constexpr int NT   = 320;   // 5 waves; wave w owns col-triples {2w, 2w+1} of 10
constexpr int XSTR = 328;   // xs stride (shorts)
constexpr int CSTR = 168;   // chs/fg stride (shorts)

// padded bf16 weight layout in ws (after c region):
//   Wbf[3][160][320], Ubf[3][160][160], Fbf[160][160]   (zero-padded)
constexpr int WB_N = 3 * 160 * 320;   // 153600
constexpr int UB_N = 3 * 160 * 160;   //  76800
constexpr int FB_N = 160 * 160;       //  25600
constexpr size_t C_FLOATS = (size_t)BATCH * CN * HD;   // 77,414,400 floats

constexpr int CH_SH = 64 * CSTR;                 // 10752 shorts (32 parents x 2 children)
constexpr int FG_SH = 64 * CSTR;                 // aliases xs (FG_SH >= 32*XSTR=10496)
constexpr int LDS_LEAF_B = 64 * XSTR * 2;        // 41,984 B (ROWS=64)
constexpr int LDS_INT_B  = (CH_SH + FG_SH) * 2;  // 43,008 B (ROWS=32)

__device__ __forceinline__ short f2bf(float f) {
    union { __bf16 b; short s; } u; u.b = (__bf16)f; return u.s;
}
__device__ __forceinline__ float bf2f(short s) {
    union { float f; unsigned u; } v; v.u = ((unsigned)(unsigned short)s) << 16; return v.f;
}
__device__ __forceinline__ float sig_(float x)  { return 1.0f / (1.0f + __expf(-x)); }
__device__ __forceinline__ float tanh_(float x) { float e = __expf(2.0f * x); return 1.0f - 2.0f / (e + 1.0f); }

__device__ __forceinline__ f32x4 MFMA(s16x8 a, s16x8 b, f32x4 c) {
    return __builtin_amdgcn_mfma_f32_16x16x32_bf16(a, b, c, 0, 0, 0);
}
} // namespace

// one-time fp32 -> zero-padded bf16 weight conversion (512 KB, L2-resident after)
__global__ __launch_bounds__(256)
void prep_w(const float* __restrict__ Wiuo, const float* __restrict__ Uiuo,
            const float* __restrict__ Ufw, short* __restrict__ dst) {
    int i = blockIdx.x * 256 + threadIdx.x;
    if (i < WB_N) {
        int g = i / (160*320); int rem = i - g*160*320; int r = rem / 320, k = rem % 320;
        float v = (r < HD && k < IDIM) ? Wiuo[(size_t)(g*HD + r)*IDIM + k] : 0.0f;
        dst[i] = f2bf(v);
    } else if (i < WB_N + UB_N) {
        int j = i - WB_N;
        int g = j / (160*160); int rem = j - g*160*160; int r = rem / 160, k = rem % 160;
        float v = (r < HD && k < HD) ? Uiuo[(size_t)(g*HD + r)*HD + k] : 0.0f;
        dst[i] = f2bf(v);
    } else if (i < WB_N + UB_N + FB_N) {
        int j = i - WB_N - UB_N; int r = j / 160, k = j % 160;
        float v = (r < HD && k < HD) ? Ufw[(size_t)r*HD + k] : 0.0f;
        dst[i] = f2bf(v);
    }
}

// MFMA lane maps (gfx950 16x16x32 bf16): A row = lane&15, B col = lane&15 (shared
// lane->k map, contiguous-8 per lane); C/D: col = lane&15, row = 4*(lane>>4)+reg.
template<bool INTERNAL, int R>
__global__ __launch_bounds__(NT)
void lvl_kernel(const float* __restrict__ x,
                const short* __restrict__ Wbf, const short* __restrict__ Ubf,
                const short* __restrict__ Fbf,
                const float* __restrict__ biuo, const float* __restrict__ Ufb,
                float* __restrict__ h_all, float* __restrict__ c_all,
                int start, int lg, int cstart)
{
    constexpr int MT = R / 16;          // row-tiles per wave
    extern __shared__ short smem[];
    short* chs = smem;                               // [64][CSTR] children h (internal)
    short* xs  = INTERNAL ? (smem + CH_SH) : smem;   // [R][XSTR] x rows
    short* fg  = xs;                                 // alias after phase A (internal)

    const int t    = threadIdx.x;
    const int wv   = t >> 6;        // 0..4
    const int ln   = t & 63;
    const int l15  = ln & 15;
    const int kg   = ln >> 4;       // 0..3
    const int row0 = blockIdx.x * R;
    const int size = 1 << lg;

    // ---------------- stage x (fp32 -> bf16 LDS, zero-padded) ----------------
    {
        constexpr int NQ = XSTR / 4;    // 82 quads/row
        for (int q = t; q < R * NQ; q += NT) {
            int lr = q / NQ, i0 = (q - lr * NQ) * 4;
            int row = row0 + lr, b = row >> lg, s = row & (size - 1);
            s16x4 v = {0,0,0,0};
            if (i0 < IDIM) {
                const float4 f = *(const float4*)(x + ((size_t)b*NN + start + s)*IDIM + i0);
                v = s16x4{ f2bf(f.x), f2bf(f.y), f2bf(f.z), f2bf(f.w) };
            }
            *(s16x4*)&xs[lr * XSTR + i0] = v;
        }
    }
    // ---------------- stage children h (internal) ----------------
    if (INTERNAL) {
        constexpr int NQ = CSTR / 4;    // 42 quads/row
        for (int q = t; q < 2 * R * NQ; q += NT) {
            int cl = q / NQ, i0 = (q - cl * NQ) * 4;
            int lr = cl >> 1, cc = cl & 1;
            int row = row0 + lr, b = row >> lg, s = row & (size - 1);
            const float* hp = h_all + ((size_t)b*NN + cstart + 2*s + cc) * HD;
            s16x4 v = {0,0,0,0};
            if (i0 + 3 < HD) {
                float2 f0 = *(const float2*)(hp + i0);
                float2 f1 = *(const float2*)(hp + i0 + 2);
                v = s16x4{ f2bf(f0.x), f2bf(f0.y), f2bf(f1.x), f2bf(f1.y) };
            } else if (i0 < HD) {       // i0 == 148
                float2 f0 = *(const float2*)(hp + i0);
                v = s16x4{ f2bf(f0.x), f2bf(f0.y), 0, 0 };
            }
            *(s16x4*)&chs[cl * CSTR + i0] = v;
        }
    }
    __syncthreads();

    // ---------------- phase A: iuo accumulators ----------------
    f32x4 acc[MT][2][3] = {};           // [row-tile][triple][gate]
    int cix[2];
    const short* wb[2][3];
    #pragma unroll
    for (int tt = 0; tt < 2; ++tt) {
        int cc = 16 * (2*wv + tt) + l15;
        cix[tt] = cc;
        #pragma unroll
        for (int g = 0; g < 3; ++g)
            wb[tt][g] = Wbf + (size_t)(g*160 + cc) * 320;
    }

    #pragma unroll
    for (int kb = 0; kb < 320; kb += 32) {
        int ka = kb + 8 * kg;
        s16x8 a[MT];
        #pragma unroll
        for (int mt = 0; mt < MT; ++mt)
            a[mt] = *(const s16x8*)&xs[(16*mt + l15) * XSTR + ka];
        #pragma unroll
        for (int tt = 0; tt < 2; ++tt)
            #pragma unroll
            for (int g = 0; g < 3; ++g) {
                s16x8 bf = *(const s16x8*)(wb[tt][g] + ka);
                #pragma unroll
                for (int mt = 0; mt < MT; ++mt)
                    acc[mt][tt][g] = MFMA(a[mt], bf, acc[mt][tt][g]);
            }
    }

    if (INTERNAL) {
        // + h_tilda @ Uiuo^T (h_tilda = child h sum, built on the fly)
        #pragma unroll
        for (int kb = 0; kb < 160; kb += 32) {
            int ka = kb + 8 * kg;
            s16x8 hs[MT];
            #pragma unroll
            for (int mt = 0; mt < MT; ++mt) {
                int pr = 16 * mt + l15;
                s16x8 h0 = *(const s16x8*)&chs[(2*pr    ) * CSTR + ka];
                s16x8 h1 = *(const s16x8*)&chs[(2*pr + 1) * CSTR + ka];
                union { bf16x8 b; s16x8 s; } u0, u1, uo;
                u0.s = h0; u1.s = h1;
                #pragma unroll
                for (int e = 0; e < 8; ++e)
                    uo.b[e] = (__bf16)((float)u0.b[e] + (float)u1.b[e]);
                hs[mt] = uo.s;
            }
            #pragma unroll
            for (int tt = 0; tt < 2; ++tt)
                #pragma unroll
                for (int g = 0; g < 3; ++g) {
                    s16x8 bf = *(const s16x8*)(Ubf + (size_t)(g*160 + cix[tt]) * 160 + ka);
                    #pragma unroll
                    for (int mt = 0; mt < MT; ++mt)
                        acc[mt][tt][g] = MFMA(hs[mt], bf, acc[mt][tt][g]);
                }
        }

        // ---------------- f-gate GEMM: f = sigmoid(ch @ Ufw^T + Ufb) ----------------
        f32x4 facc[4][2] = {};          // [child row-tile][col-tile]
        int fcix[2];
        #pragma unroll
        for (int ct = 0; ct < 2; ++ct) fcix[ct] = 16 * (2*wv + ct) + l15;
        #pragma unroll
        for (int kb = 0; kb < 160; kb += 32) {
            int ka = kb + 8 * kg;
            s16x8 af[4];
            #pragma unroll
            for (int rt = 0; rt < 4; ++rt)
                af[rt] = *(const s16x8*)&chs[(16*rt + l15) * CSTR + ka];
            #pragma unroll
            for (int ct = 0; ct < 2; ++ct) {
                s16x8 bf = *(const s16x8*)(Fbf + (size_t)fcix[ct] * 160 + ka);
                #pragma unroll
                for (int rt = 0; rt < 4; ++rt)
                    facc[rt][ct] = MFMA(af[rt], bf, facc[rt][ct]);
            }
        }
        __syncthreads();    // xs dead -> reuse as fg
        #pragma unroll
        for (int ct = 0; ct < 2; ++ct) {
            if (fcix[ct] < HD) {
                float fbias = Ufb[fcix[ct]];
                #pragma unroll
                for (int rt = 0; rt < 4; ++rt)
                    #pragma unroll
                    for (int r = 0; r < 4; ++r) {
                        int crow = 16*rt + 4*kg + r;
                        fg[crow * CSTR + fcix[ct]] = f2bf(sig_(facc[rt][ct][r] + fbias));
                    }
            }
        }
        __syncthreads();
    }

    // ---------------- epilogue: gates, csum, write h & c ----------------
    #pragma unroll
    for (int tt = 0; tt < 2; ++tt) {
        int c = cix[tt];
        if (c >= HD) continue;
        float bi = biuo[c], bu = biuo[HD + c], bo = biuo[2*HD + c];
        #pragma unroll
        for (int mt = 0; mt < MT; ++mt)
            #pragma unroll
            for (int r = 0; r < 4; ++r) {
                int pl = 16*mt + 4*kg + r;
                int row = row0 + pl, b = row >> lg, s = row & (size - 1);
                float ig = acc[mt][tt][0][r] + bi;
                float ug = acc[mt][tt][1][r] + bu;
                float og = acc[mt][tt][2][r] + bo;
                float csum = 0.0f;
                if (INTERNAL) {
                    int cl = 2 * pl;
                    float f0 = bf2f(fg[(cl    ) * CSTR + c]);
                    float f1 = bf2f(fg[(cl + 1) * CSTR + c]);
                    // children c at nodes cstart+2s(+1); c scratch indexed by node-1
                    const float* cp = c_all + ((size_t)b*CN + cstart + 2*s - 1) * HD + c;
                    csum = f0 * cp[0] + f1 * cp[HD];
                }
                float cn = sig_(ig) * tanh_(ug) + csum;
                float hn = sig_(og) * tanh_(cn);
                h_all[((size_t)b*NN + start + s) * HD + c] = hn;
                if (start > 0)   // root c never read
                    c_all[((size_t)b*CN + start + s - 1) * HD + c] = cn;
            }
    }
}

extern "C" void kernel_launch(void* const* d_in, const int* in_sizes, int n_in,
                              void* d_out, int out_size, void* d_ws, size_t ws_size,
                              hipStream_t stream) {
    const float* x    = (const float*)d_in[0];
    const float* Wiuo = (const float*)d_in[1];
    const float* Uiuo = (const float*)d_in[2];
    const float* biuo = (const float*)d_in[3];
    const float* Ufw  = (const float*)d_in[4];
    const float* Ufb  = (const float*)d_in[5];
    float* h = (float*)d_out;
    float* c = (float*)d_ws;                         // 309.7 MB (126 nodes)
    short* wbf = (short*)((float*)d_ws + C_FLOATS);  // +512 KB padded bf16 weights
    const short* Wbf = wbf;
    const short* Ubf = wbf + WB_N;
    const short* Fbf = wbf + WB_N + UB_N;

    (void)hipFuncSetAttribute((const void*)lvl_kernel<false,64>,
                              hipFuncAttributeMaxDynamicSharedMemorySize, 64 * 1024);
    (void)hipFuncSetAttribute((const void*)lvl_kernel<true,32>,
                              hipFuncAttributeMaxDynamicSharedMemorySize, 64 * 1024);

    prep_w<<<(WB_N + UB_N + FB_N + 255) / 256, 256, 0, stream>>>(Wiuo, Uiuo, Ufw, wbf);

    for (int d = DEPTH_ - 1; d >= 0; --d) {
        const int size   = 1 << d;
        const int start  = size - 1;
        const int cstart = 2 * size - 1;
        if (d == DEPTH_ - 1) {
            const int blocks = (BATCH * size) / 64;
            lvl_kernel<false,64><<<blocks, NT, LDS_LEAF_B, stream>>>(
                x, Wbf, Ubf, Fbf, biuo, Ufb, h, c, start, d, cstart);
        } else {
            const int blocks = (BATCH * size) / 32;
            lvl_kernel<true,32><<<blocks, NT, LDS_INT_B, stream>>>(
                x, Wbf, Ubf, Fbf, biuo, Ufb, h, c, start, d, cstart);
        }
    }
}

// Round 5
// 1279.250 us; speedup vs baseline: 15.0552x; 1.2248x over previous
//
#include <hip/hip_runtime.h>

typedef float  f32x4  __attribute__((ext_vector_type(4)));
typedef short  s16x8  __attribute__((ext_vector_type(8)));
typedef short  s16x4  __attribute__((ext_vector_type(4)));
typedef __bf16 bf16x8 __attribute__((ext_vector_type(8)));

namespace {
constexpr int BATCH = 4096, DEPTH_ = 7, NN = 127, CN = 126, IDIM = 300, HD = 150;
constexpr int NW = 10, NT = 640;      // 10 waves; wave w owns col-triple w (cols 16w+l of each gate)
constexpr int XSTR = 328;             // xs stride (shorts)
constexpr int CSTR = 164;             // chs/fg stride (shorts)
constexpr int BCS  = 40;              // B-slab col stride (shorts): 80 B, 16B-aligned, 18-dword bank walk

// weight slabs in ws (per 32-K chunk), padded to 1 KiB multiples for chunked staging
constexpr int WSLAB = 19456;          // shorts: 480*40=19200 content + pad  (38 KiB-chunks)
constexpr int FSLAB = 6656;           // shorts: 160*40= 6400 content + pad  (13 chunks)
constexpr int WCH = 38, FCH = 13;     // 1-KiB chunks per slab
constexpr int W_SH = 10 * WSLAB, U_SH = 5 * WSLAB, F_SH = 5 * FSLAB;
constexpr size_t C_FLOATS = (size_t)BATCH * CN * HD;   // 309.7 MB c-scratch (nodes 1..126)

// LDS (shorts): leaf: xs[128][XSTR] | B[2][WSLAB]; internal: chs[128][CSTR] xs[64][XSTR](=fg) | B[2][WSLAB]
constexpr int LEAF_XS = 128 * XSTR;   // 41984
constexpr int INT_CHS = 128 * CSTR;   // 20992
constexpr int INT_XS  = 64 * XSTR;    // 20992
constexpr int LDS_LEAF_B = (LEAF_XS + 2 * WSLAB) * 2;            // 161792
constexpr int LDS_INT_B  = (INT_CHS + INT_XS + 2 * WSLAB) * 2;   // 161792

__device__ __forceinline__ short f2bf(float f) {
    union { __bf16 b; short s; } u; u.b = (__bf16)f; return u.s;
}
__device__ __forceinline__ float bf2f(short s) {
    union { float f; unsigned u; } v; v.u = ((unsigned)(unsigned short)s) << 16; return v.f;
}
__device__ __forceinline__ float sig_(float x)  { return 1.0f / (1.0f + __expf(-x)); }
__device__ __forceinline__ float tanh_(float x) { float e = __expf(2.0f * x); return 1.0f - 2.0f / (e + 1.0f); }

__device__ __forceinline__ f32x4 MFMA(s16x8 a, s16x8 b, f32x4 c) {
    return __builtin_amdgcn_mfma_f32_16x16x32_bf16(a, b, c, 0, 0, 0);
}

typedef const __attribute__((address_space(1))) unsigned int* gp_t;
typedef __attribute__((address_space(3))) unsigned int* lp_t;
// stage one slab global->LDS: linear copy, 1-KiB wave-chunks, 16B/lane
__device__ __forceinline__ void stage_slab(const short* g, short* l, int nch, int wv, int ln) {
    const char* gb = (const char*)g;
    char* lb = (char*)l;
    for (int c = wv; c < nch; c += NW)
        __builtin_amdgcn_global_load_lds((gp_t)(gb + c * 1024 + ln * 16),
                                         (lp_t)(lb + c * 1024 + ln * 16), 16, 0, 0);
}
} // namespace

// one-time weight pre-blocking: fp32 -> bf16 K-chunk slabs [cs][40] (zero-padded)
__global__ __launch_bounds__(256)
void prep_w(const float* __restrict__ Wiuo, const float* __restrict__ Uiuo,
            const float* __restrict__ Ufw, short* __restrict__ dst) {
    int i = blockIdx.x * 256 + threadIdx.x;
    short v = 0;
    if (i < W_SH) {
        int kb = i / WSLAB, r = i - kb * WSLAB;
        if (r < 480 * BCS) {
            int cs = r / BCS, j = r - cs * BCS;
            int g = cs / 160, cp = cs - g * 160, k = kb * 32 + j;
            if (cp < HD && j < 32 && k < IDIM) v = f2bf(Wiuo[(size_t)(g*HD + cp)*IDIM + k]);
        }
        dst[i] = v;
    } else if (i < W_SH + U_SH) {
        int q = i - W_SH;
        int kb = q / WSLAB, r = q - kb * WSLAB;
        if (r < 480 * BCS) {
            int cs = r / BCS, j = r - cs * BCS;
            int g = cs / 160, cp = cs - g * 160, k = kb * 32 + j;
            if (cp < HD && j < 32 && k < HD) v = f2bf(Uiuo[(size_t)(g*HD + cp)*HD + k]);
        }
        dst[i] = v;
    } else if (i < W_SH + U_SH + F_SH) {
        int q = i - W_SH - U_SH;
        int kb = q / FSLAB, r = q - kb * FSLAB;
        if (r < 160 * BCS) {
            int cs = r / BCS, j = r - cs * BCS, k = kb * 32 + j;
            if (cs < HD && j < 32 && k < HD) v = f2bf(Ufw[(size_t)cs*HD + k]);
        }
        dst[i] = v;
    }
}

// MFMA lane maps (gfx950 16x16x32 bf16): A row = lane&15, B col = lane&15 (shared
// lane->k map); C/D: col = lane&15, row = 4*(lane>>4)+reg.
template<bool INTERNAL>
__global__ __launch_bounds__(NT)
void lvl_kernel(const float* __restrict__ x,
                const short* __restrict__ Wsl, const short* __restrict__ Usl,
                const short* __restrict__ Fsl,
                const float* __restrict__ biuo, const float* __restrict__ Ufb,
                float* __restrict__ h_all, float* __restrict__ c_all,
                int start, int lg, int cstart)
{
    constexpr int MT = INTERNAL ? 4 : 8;
    constexpr int BM = 16 * MT;
    extern __shared__ short smem[];
    short* chs = smem;                                       // internal: [128][CSTR]
    short* xs  = INTERNAL ? (smem + INT_CHS) : smem;         // [BM][XSTR]
    short* fg  = xs;                                         // internal alias after x-GEMM
    short* B0  = INTERNAL ? (smem + INT_CHS + INT_XS) : (smem + LEAF_XS);
    short* B1  = B0 + WSLAB;

    const int t    = threadIdx.x;
    const int wv   = t >> 6;        // 0..9  (col-triple)
    const int ln   = t & 63;
    const int l15  = ln & 15;
    const int kg   = ln >> 4;       // 0..3
    const int row0 = blockIdx.x * BM;
    const int size = 1 << lg;
    const int c16  = 16 * wv;       // this wave's column base within each gate

    // ---------------- prologue: stage xs (+chs), issue W slab 0 ----------------
    stage_slab(Wsl, B0, WCH, wv, ln);
    {
        constexpr int NQ = XSTR / 4;    // 82 quads/row
        for (int q = t; q < BM * NQ; q += NT) {
            int lr = q / NQ, i0 = (q - lr * NQ) * 4;
            int row = row0 + lr, b = row >> lg, s = row & (size - 1);
            s16x4 v = {0,0,0,0};
            if (i0 < IDIM) {
                const float4 f = *(const float4*)(x + ((size_t)b*NN + start + s)*IDIM + i0);
                v = s16x4{ f2bf(f.x), f2bf(f.y), f2bf(f.z), f2bf(f.w) };
            }
            *(s16x4*)&xs[lr * XSTR + i0] = v;
        }
    }
    if (INTERNAL) {
        constexpr int NQ = CSTR / 4;    // 41 quads/row
        for (int q = t; q < 2 * BM * NQ; q += NT) {
            int cl = q / NQ, i0 = (q - cl * NQ) * 4;
            int lr = cl >> 1, cc = cl & 1;
            int row = row0 + lr, b = row >> lg, s = row & (size - 1);
            const float* hp = h_all + ((size_t)b*NN + cstart + 2*s + cc) * HD;
            s16x4 v = {0,0,0,0};
            if (i0 + 3 < HD) {
                float2 f0 = *(const float2*)(hp + i0);
                float2 f1 = *(const float2*)(hp + i0 + 2);
                v = s16x4{ f2bf(f0.x), f2bf(f0.y), f2bf(f1.x), f2bf(f1.y) };
            } else if (i0 < HD) {       // i0 == 148
                float2 f0 = *(const float2*)(hp + i0);
                v = s16x4{ f2bf(f0.x), f2bf(f0.y), 0, 0 };
            }
            *(s16x4*)&chs[cl * CSTR + i0] = v;
        }
    }
    __syncthreads();

    f32x4 acc[MT][3] = {};      // [row-tile][gate]

    // ---------------- x @ W^T  (K=320, 10 chunks) ----------------
    #pragma unroll
    for (int kb = 0; kb < 10; ++kb) {
        short* bcur = (kb & 1) ? B1 : B0;
        short* bnxt = (kb & 1) ? B0 : B1;
        if (kb < 9)            stage_slab(Wsl + (kb+1)*WSLAB, bnxt, WCH, wv, ln);
        else if (INTERNAL)     stage_slab(Usl, bnxt, WCH, wv, ln);
        s16x8 a[MT];
        #pragma unroll
        for (int mt = 0; mt < MT; ++mt)
            a[mt] = *(const s16x8*)&xs[(16*mt + l15) * XSTR + kb*32 + kg*8];
        #pragma unroll
        for (int g = 0; g < 3; ++g) {
            s16x8 bf = *(const s16x8*)&bcur[(g*160 + c16 + l15) * BCS + kg*8];
            #pragma unroll
            for (int mt = 0; mt < MT; ++mt)
                acc[mt][g] = MFMA(a[mt], bf, acc[mt][g]);
        }
        __syncthreads();
    }

    f32x4 facc[2*MT] = {};      // internal: f-gate acc per child row-tile

    if (INTERNAL) {
        // ---------------- + h_tilda @ U^T (K=160, 5 chunks) ----------------
        #pragma unroll
        for (int ku = 0; ku < 5; ++ku) {
            int s = 10 + ku;
            short* bcur = (s & 1) ? B1 : B0;
            short* bnxt = (s & 1) ? B0 : B1;
            if (ku < 4) stage_slab(Usl + (ku+1)*WSLAB, bnxt, WCH, wv, ln);
            else        stage_slab(Fsl, bnxt, FCH, wv, ln);
            int ka = ku*32 + kg*8;
            s16x8 hs[MT];
            #pragma unroll
            for (int mt = 0; mt < MT; ++mt) {
                int pr = 16*mt + l15;
                s16x8 h0 = *(const s16x8*)&chs[(2*pr    ) * CSTR + ka];
                s16x8 h1 = *(const s16x8*)&chs[(2*pr + 1) * CSTR + ka];
                union { bf16x8 b; s16x8 s; } u0, u1, uo;
                u0.s = h0; u1.s = h1;
                #pragma unroll
                for (int e = 0; e < 8; ++e)
                    uo.b[e] = (__bf16)((float)u0.b[e] + (float)u1.b[e]);
                hs[mt] = uo.s;
            }
            #pragma unroll
            for (int g = 0; g < 3; ++g) {
                s16x8 bf = *(const s16x8*)&bcur[(g*160 + c16 + l15) * BCS + kg*8];
                #pragma unroll
                for (int mt = 0; mt < MT; ++mt)
                    acc[mt][g] = MFMA(hs[mt], bf, acc[mt][g]);
            }
            __syncthreads();
        }

        // ---------------- f = ch @ F^T (K=160, 5 chunks) ----------------
        #pragma unroll
        for (int kf = 0; kf < 5; ++kf) {
            int s = 15 + kf;
            short* bcur = (s & 1) ? B1 : B0;
            short* bnxt = (s & 1) ? B0 : B1;
            if (kf < 4) stage_slab(Fsl + (kf+1)*FSLAB, bnxt, FCH, wv, ln);
            int ka = kf*32 + kg*8;
            s16x8 bf = *(const s16x8*)&bcur[(c16 + l15) * BCS + kg*8];
            #pragma unroll
            for (int rt = 0; rt < 2*MT; ++rt) {
                s16x8 af = *(const s16x8*)&chs[(16*rt + l15) * CSTR + ka];
                facc[rt] = MFMA(af, bf, facc[rt]);
            }
            __syncthreads();
        }

        // write f-gates (sigmoid) into fg (aliases dead xs)
        {
            int c = c16 + l15;
            if (c < HD) {
                float fb_ = Ufb[c];
                #pragma unroll
                for (int rt = 0; rt < 2*MT; ++rt)
                    #pragma unroll
                    for (int r = 0; r < 4; ++r) {
                        int crow = 16*rt + 4*kg + r;
                        fg[crow * CSTR + c] = f2bf(sig_(facc[rt][r] + fb_));
                    }
            }
        }
        __syncthreads();
    }

    // ---------------- epilogue ----------------
    {
        int c = c16 + l15;
        if (c < HD) {
            float bi = biuo[c], bu = biuo[HD + c], bo = biuo[2*HD + c];
            #pragma unroll
            for (int mt = 0; mt < MT; ++mt)
                #pragma unroll
                for (int r = 0; r < 4; ++r) {
                    int pl = 16*mt + 4*kg + r;
                    int row = row0 + pl, b = row >> lg, s = row & (size - 1);
                    float ig = acc[mt][0][r] + bi;
                    float ug = acc[mt][1][r] + bu;
                    float og = acc[mt][2][r] + bo;
                    float csum = 0.0f;
                    if (INTERNAL) {
                        int cl = 2 * pl;
                        float f0 = bf2f(fg[(cl    ) * CSTR + c]);
                        float f1 = bf2f(fg[(cl + 1) * CSTR + c]);
                        const float* cp = c_all + ((size_t)b*CN + cstart + 2*s - 1) * HD + c;
                        csum = f0 * cp[0] + f1 * cp[HD];
                    }
                    float cn = sig_(ig) * tanh_(ug) + csum;
                    float hn = sig_(og) * tanh_(cn);
                    h_all[((size_t)b*NN + start + s) * HD + c] = hn;
                    if (start > 0)
                        c_all[((size_t)b*CN + start + s - 1) * HD + c] = cn;
                }
        }
    }
}

extern "C" void kernel_launch(void* const* d_in, const int* in_sizes, int n_in,
                              void* d_out, int out_size, void* d_ws, size_t ws_size,
                              hipStream_t stream) {
    const float* x    = (const float*)d_in[0];
    const float* Wiuo = (const float*)d_in[1];
    const float* Uiuo = (const float*)d_in[2];
    const float* biuo = (const float*)d_in[3];
    const float* Ufw  = (const float*)d_in[4];
    const float* Ufb  = (const float*)d_in[5];
    float* h = (float*)d_out;
    float* c = (float*)d_ws;                            // 309.7 MB (nodes 1..126)
    short* wsl = (short*)((float*)d_ws + C_FLOATS);     // +640 KB weight slabs
    const short* Wsl = wsl;
    const short* Usl = wsl + W_SH;
    const short* Fsl = wsl + W_SH + U_SH;

    (void)hipFuncSetAttribute((const void*)lvl_kernel<false>,
                              hipFuncAttributeMaxDynamicSharedMemorySize, 160 * 1024);
    (void)hipFuncSetAttribute((const void*)lvl_kernel<true>,
                              hipFuncAttributeMaxDynamicSharedMemorySize, 160 * 1024);

    prep_w<<<(W_SH + U_SH + F_SH + 255) / 256, 256, 0, stream>>>(Wiuo, Uiuo, Ufw, wsl);

    for (int d = DEPTH_ - 1; d >= 0; --d) {
        const int size   = 1 << d;
        const int start  = size - 1;
        const int cstart = 2 * size - 1;
        if (d == DEPTH_ - 1) {
            const int blocks = (BATCH * size) / 128;
            lvl_kernel<false><<<blocks, NT, LDS_LEAF_B, stream>>>(
                x, Wsl, Usl, Fsl, biuo, Ufb, h, c, start, d, cstart);
        } else {
            const int blocks = (BATCH * size) / 64;
            lvl_kernel<true><<<blocks, NT, LDS_INT_B, stream>>>(
                x, Wsl, Usl, Fsl, biuo, Ufb, h, c, start, d, cstart);
        }
    }
}

// Round 6
// 1103.835 us; speedup vs baseline: 17.4477x; 1.1589x over previous
//
#include <hip/hip_runtime.h>

typedef float  f32x4  __attribute__((ext_vector_type(4)));
typedef short  s16x8  __attribute__((ext_vector_type(8)));
typedef short  s16x4  __attribute__((ext_vector_type(4)));
typedef _Float16 f16;

namespace {
constexpr int BATCH = 4096, NN = 127, IDIM = 300, HD = 150;
constexpr int NT = 640, NW = 10;
constexpr int XSTR = 324;            // xs stride (shorts): 162 dw, gcd(162,32)=2 -> 16 banks
constexpr int BCS  = 36;             // W-slab col stride (shorts): 18 dw -> 16 banks
constexpr int WSLAB = 17408;         // shorts (34 KiB; content 480*36=17280 + pad)
constexpr int WCH = 34;              // 1-KiB staging chunks per slab
constexpr int CSTR = 164;            // chs stride (shorts): 82 dw -> 16 banks

// ws layout (halves): cA | cB | iuoA | iuoB | slabs
constexpr size_t CA_N   = (size_t)BATCH * 64 * HD;        // 39,321,600  (levels 6,4,2,0)
constexpr size_t CB_N   = (size_t)BATCH * 32 * HD;        // 19,660,800  (levels 5,3,1)
constexpr size_t IUOA_N = (size_t)BATCH * 32 * 456;       // 59,768,832  (levels 5,3,1)
constexpr size_t IUOB_N = (size_t)BATCH * 16 * 456;       // 29,884,416  (levels 4,2,0)
constexpr int W_SH = 10 * WSLAB;      // 174,080
constexpr int U_SH = 480 * 160;       //  76,800   plain [col][k]
constexpr int F_SH = 160 * 160;       //  25,600   plain [col][k]

constexpr int HEAVY_LDS = (64 * XSTR + WSLAB) * 2;        // 76,288 B -> 2 blocks/CU

__device__ __forceinline__ short f2bf(float f) {
    union { __bf16 b; short s; } u; u.b = (__bf16)f; return u.s;
}
__device__ __forceinline__ float bf2f(short s) {
    union { float f; unsigned u; } v; v.u = ((unsigned)(unsigned short)s) << 16; return v.f;
}
__device__ __forceinline__ float sig_(float x)  { return 1.0f / (1.0f + __expf(-x)); }
__device__ __forceinline__ float tanh_(float x) { float e = __expf(2.0f * x); return 1.0f - 2.0f / (e + 1.0f); }
__device__ __forceinline__ s16x4 cvt4(float a,float b,float c,float d) {
    return s16x4{ f2bf(a), f2bf(b), f2bf(c), f2bf(d) };
}
__device__ __forceinline__ s16x8 cat(s16x4 lo, s16x4 hi) {
    return __builtin_shufflevector(lo, hi, 0,1,2,3,4,5,6,7);
}
__device__ __forceinline__ f32x4 MFMA(s16x8 a, s16x8 b, f32x4 c) {
    return __builtin_amdgcn_mfma_f32_16x16x32_bf16(a, b, c, 0, 0, 0);
}

typedef const __attribute__((address_space(1))) unsigned int* gp_t;
typedef __attribute__((address_space(3))) unsigned int* lp_t;
__device__ __forceinline__ void stage_slab(const short* g, short* l, int nch, int wv, int ln) {
    const char* gb = (const char*)g;
    char* lb = (char*)l;
    for (int c = wv; c < nch; c += NW)
        __builtin_amdgcn_global_load_lds((gp_t)(gb + c * 1024 + ln * 16),
                                         (lp_t)(lb + c * 1024 + ln * 16), 16, 0, 0);
}
} // namespace

// -------- one-time weight prep: W -> K-chunked bf16 slabs; U,F -> plain [col][k] bf16 --------
__global__ __launch_bounds__(256)
void prep_w(const float* __restrict__ Wiuo, const float* __restrict__ Uiuo,
            const float* __restrict__ Ufw, short* __restrict__ dst) {
    int i = blockIdx.x * 256 + threadIdx.x;
    short v = 0;
    if (i < W_SH) {
        int kc = i / WSLAB, r = i - kc * WSLAB;
        if (r < 480 * BCS) {
            int col = r / BCS, j = r - col * BCS;
            int g = col / 160, cp = col - g * 160, k = kc * 32 + j;
            if (cp < HD && j < 32 && k < IDIM) v = f2bf(Wiuo[(size_t)(g*HD + cp)*IDIM + k]);
        }
        dst[i] = v;
    } else if (i < W_SH + U_SH) {
        int q = i - W_SH;
        int col = q / 160, k = q - col * 160;
        int g = col / 160 >= 3 ? 2 : col / 160;  // col<480
        g = col / 160; int cp = col - g * 160;
        if (cp < HD && k < HD) v = f2bf(Uiuo[(size_t)(g*HD + cp)*HD + k]);
        dst[i] = v;
    } else if (i < W_SH + U_SH + F_SH) {
        int q = i - W_SH - U_SH;
        int col = q / 160, k = q - col * 160;
        if (col < HD && k < HD) v = f2bf(Ufw[(size_t)col*HD + k]);
        dst[i] = v;
    }
}

// -------- heavy: pure x@W GEMM per level. LEAF: fused gates; else: write iuo fp16 --------
// MFMA maps: A row=lane&15, B col=lane&15 (shared lane->k); C/D col=lane&15, row=4*(lane>>4)+reg.
template<bool LEAF>
__global__ __launch_bounds__(NT, 5)
void gemm_x(const float* __restrict__ x, const short* __restrict__ Wsl,
            const float* __restrict__ biuo, float* __restrict__ h_all,
            f16* __restrict__ c_slot, f16* __restrict__ iuo_slot,
            int start, int lg)
{
    extern __shared__ short smem[];
    short* xs  = smem;              // [64][324] bf16
    short* wsl = smem + 64 * XSTR;  // [17408]

    const int t   = threadIdx.x;
    const int wv  = t >> 6, ln = t & 63, l15 = ln & 15, kg = ln >> 4;
    const int row0 = blockIdx.x * 64;
    const int mask = (1 << lg) - 1;
    const int c16 = wv * 16;

    stage_slab(Wsl, wsl, WCH, wv, ln);
    // stage x: thread (row=t&63, seg=wv) covers elems [32*seg, 32*seg+32) (seg 9: tail+zeros)
    {
        int lr = t & 63, seg = wv;
        int row = row0 + lr, b = row >> lg, s = row & mask;
        const float* xp = x + ((size_t)b*NN + start + s) * IDIM;
        short* dst = &xs[lr * XSTR];
        if (seg < 9) {
            int e0 = seg * 32;
            #pragma unroll
            for (int q = 0; q < 8; ++q) {
                float4 f = *(const float4*)(xp + e0 + 4*q);
                *(s16x4*)&dst[e0 + 4*q] = cvt4(f.x, f.y, f.z, f.w);
            }
        } else {
            #pragma unroll
            for (int q = 0; q < 3; ++q) {
                float4 f = *(const float4*)(xp + 288 + 4*q);
                *(s16x4*)&dst[288 + 4*q] = cvt4(f.x, f.y, f.z, f.w);
            }
            #pragma unroll
            for (int q = 0; q < 6; ++q) *(s16x4*)&dst[300 + 4*q] = s16x4{0,0,0,0};
        }
    }
    __syncthreads();

    f32x4 acc[4][3] = {};
    #pragma unroll
    for (int kc = 0; kc < 10; ++kc) {
        int ka = kc * 32 + kg * 8;
        s16x8 a[4];
        #pragma unroll
        for (int mt = 0; mt < 4; ++mt) {
            const short* p = &xs[(16*mt + l15) * XSTR + ka];
            a[mt] = cat(*(const s16x4*)p, *(const s16x4*)(p + 4));
        }
        #pragma unroll
        for (int g = 0; g < 3; ++g) {
            const short* p = &wsl[(g*160 + c16 + l15) * BCS + kg * 8];
            s16x8 bf = cat(*(const s16x4*)p, *(const s16x4*)(p + 4));
            #pragma unroll
            for (int mt = 0; mt < 4; ++mt)
                acc[mt][g] = MFMA(a[mt], bf, acc[mt][g]);
        }
        if (kc < 9) {
            __syncthreads();
            stage_slab(Wsl + (kc+1) * WSLAB, wsl, WCH, wv, ln);
            __syncthreads();
        }
    }

    // epilogue
    int c = c16 + l15;
    if (c < HD) {
        if (LEAF) {
            float bi = biuo[c], bu = biuo[HD + c], bo = biuo[2*HD + c];
            #pragma unroll
            for (int mt = 0; mt < 4; ++mt)
                #pragma unroll
                for (int r = 0; r < 4; ++r) {
                    int pl = 16*mt + 4*kg + r;
                    int row = row0 + pl, b = row >> 6, n = row & 63;
                    float cn = sig_(acc[mt][0][r] + bi) * tanh_(acc[mt][1][r] + bu);
                    float hn = sig_(acc[mt][2][r] + bo) * tanh_(cn);
                    h_all[((size_t)b*NN + 63 + n) * HD + c] = hn;
                    c_slot[((size_t)(b*64 + n)) * HD + c] = (f16)cn;
                }
        } else {
            #pragma unroll
            for (int mt = 0; mt < 4; ++mt)
                #pragma unroll
                for (int r = 0; r < 4; ++r) {
                    int row = row0 + 16*mt + 4*kg + r;
                    f16* ip = iuo_slot + (size_t)row * 456;
                    ip[c]        = (f16)acc[mt][0][r];
                    ip[152 + c]  = (f16)acc[mt][1][r];
                    ip[304 + c]  = (f16)acc[mt][2][r];
                }
        }
    }
}

// -------- light: per internal level. 16 parents/block, 10 waves, 2 barriers --------
__global__ __launch_bounds__(NT, 5)
void lvl_light(const short* __restrict__ Ubf, const short* __restrict__ Fbf,
               const float* __restrict__ biuo, const float* __restrict__ Ufb,
               const f16* __restrict__ iuo_slot, const f16* __restrict__ cprev,
               f16* __restrict__ cmine, float* __restrict__ h_all,
               int start, int lg, int cstart)
{
    __shared__ short chs[2][16][CSTR];   // [plane=child][parent][k] bf16
    __shared__ short fgs[NW][32][16];    // per-wave f-gates [child-major rows][col]

    const int t = threadIdx.x;
    const int wv = t >> 6, ln = t & 63, l15 = ln & 15, kg = ln >> 4;
    const int row0 = blockIdx.x * 16;
    const int mask = (1 << lg) - 1;
    const int c = wv * 16 + l15;     // 0..159 (padded col)

    // stage children h (fp32 global -> bf16 LDS), one (rc,part) per thread
    {
        int rc = t & 31, part = t >> 5;          // part 0..19 covers k [0,160)
        int plane = rc >> 4, lr = rc & 15;
        int row = row0 + lr, b = row >> lg, s = row & mask;
        const float* hp = h_all + ((size_t)b*NN + cstart + 2*s + plane) * HD;
        short* dst = &chs[plane][lr][part * 8];
        if (part < 18) {
            float4 f0 = *(const float4*)(hp + part*8);
            float4 f1 = *(const float4*)(hp + part*8 + 4);
            *(s16x4*)dst       = cvt4(f0.x, f0.y, f0.z, f0.w);
            *(s16x4*)(dst + 4) = cvt4(f1.x, f1.y, f1.z, f1.w);
        } else if (part == 18) {
            float4 f0 = *(const float4*)(hp + 144);
            float2 f1 = *(const float2*)(hp + 148);
            *(s16x4*)dst       = cvt4(f0.x, f0.y, f0.z, f0.w);
            *(s16x4*)(dst + 4) = s16x4{ f2bf(f1.x), f2bf(f1.y), 0, 0 };
        } else {
            *(s16x4*)dst = s16x4{0,0,0,0};
            *(s16x4*)(dst + 4) = s16x4{0,0,0,0};
        }
    }
    __syncthreads();

    // ---- F phase: f = sigmoid(ch @ F^T + b) for this wave's 16 cols ----
    f32x4 facc[2] = {};
    #pragma unroll
    for (int kc = 0; kc < 5; ++kc) {
        int ka = kc * 32 + kg * 8;
        s16x8 bf = *(const s16x8*)(Fbf + (size_t)c * 160 + ka);
        #pragma unroll
        for (int rt = 0; rt < 2; ++rt) {
            const short* p = &chs[rt][l15][ka];
            s16x8 af = cat(*(const s16x4*)p, *(const s16x4*)(p + 4));
            facc[rt] = MFMA(af, bf, facc[rt]);
        }
    }
    {
        float fb_ = (c < HD) ? Ufb[c] : 0.0f;
        #pragma unroll
        for (int rt = 0; rt < 2; ++rt)
            #pragma unroll
            for (int r = 0; r < 4; ++r)
                fgs[wv][rt*16 + 4*kg + r][l15] = f2bf(sig_(facc[rt][r] + fb_));
    }
    __syncthreads();

    // ---- U phase: acc = h_tilda @ U^T ----
    f32x4 acc[3] = {};
    #pragma unroll
    for (int kc = 0; kc < 5; ++kc) {
        int ka = kc * 32 + kg * 8;
        const short* p0 = &chs[0][l15][ka];
        const short* p1 = &chs[1][l15][ka];
        s16x8 h0 = cat(*(const s16x4*)p0, *(const s16x4*)(p0 + 4));
        s16x8 h1 = cat(*(const s16x4*)p1, *(const s16x4*)(p1 + 4));
        s16x8 hs;
        #pragma unroll
        for (int e = 0; e < 8; ++e)
            hs[e] = f2bf(bf2f(h0[e]) + bf2f(h1[e]));
        #pragma unroll
        for (int g = 0; g < 3; ++g) {
            s16x8 bf = *(const s16x8*)(Ubf + (size_t)(g*160 + c) * 160 + ka);
            acc[g] = MFMA(hs, bf, acc[g]);
        }
    }

    // ---- epilogue ----
    if (c < HD) {
        float bi = biuo[c], bu = biuo[HD + c], bo = biuo[2*HD + c];
        #pragma unroll
        for (int r = 0; r < 4; ++r) {
            int pl = 4*kg + r;
            int row = row0 + pl, b = row >> lg, s = row & mask;
            const f16* ip = iuo_slot + (size_t)row * 456;
            float ig = (float)ip[c]       + bi + acc[0][r];
            float ug = (float)ip[152 + c] + bu + acc[1][r];
            float og = (float)ip[304 + c] + bo + acc[2][r];
            float f0 = bf2f(fgs[wv][pl][l15]);
            float f1 = bf2f(fgs[wv][16 + pl][l15]);
            size_t cb = ((size_t)b << (lg + 1)) + 2*s;
            float c0 = (float)cprev[(cb    ) * HD + c];
            float c1 = (float)cprev[(cb + 1) * HD + c];
            float cn = sig_(ig) * tanh_(ug) + f0*c0 + f1*c1;
            float hn = sig_(og) * tanh_(cn);
            h_all[((size_t)b*NN + start + s) * HD + c] = hn;
            cmine[(((size_t)b << lg) + s) * HD + c] = (f16)cn;
        }
    }
}

extern "C" void kernel_launch(void* const* d_in, const int* in_sizes, int n_in,
                              void* d_out, int out_size, void* d_ws, size_t ws_size,
                              hipStream_t stream) {
    const float* x    = (const float*)d_in[0];
    const float* Wiuo = (const float*)d_in[1];
    const float* Uiuo = (const float*)d_in[2];
    const float* biuo = (const float*)d_in[3];
    const float* Ufw  = (const float*)d_in[4];
    const float* Ufb  = (const float*)d_in[5];
    float* h = (float*)d_out;

    f16* cA   = (f16*)d_ws;
    f16* cB   = cA + CA_N;
    f16* iuoA = cB + CB_N;
    f16* iuoB = iuoA + IUOA_N;
    short* slabs = (short*)(iuoB + IUOB_N);      // total ~297.8 MB
    const short* Wsl = slabs;
    const short* Ubf = slabs + W_SH;
    const short* Fbf = slabs + W_SH + U_SH;

    (void)hipFuncSetAttribute((const void*)gemm_x<true>,
                              hipFuncAttributeMaxDynamicSharedMemorySize, 160 * 1024);
    (void)hipFuncSetAttribute((const void*)gemm_x<false>,
                              hipFuncAttributeMaxDynamicSharedMemorySize, 160 * 1024);

    prep_w<<<(W_SH + U_SH + F_SH + 255) / 256, 256, 0, stream>>>(Wiuo, Uiuo, Ufw, slabs);

    // leaf level (d=6): fused gates
    gemm_x<true><<<4096, NT, HEAVY_LDS, stream>>>(x, Wsl, biuo, h, cA, nullptr, 63, 6);

    for (int d = 5; d >= 0; --d) {
        f16* islot = (d & 1) ? iuoA : iuoB;
        f16* cprev = ((d + 1) & 1) ? cB : cA;
        f16* cmine = (d & 1) ? cB : cA;
        const int start = (1 << d) - 1, cstart = (1 << (d+1)) - 1;
        gemm_x<false><<<64 << d, NT, HEAVY_LDS, stream>>>(x, Wsl, biuo, h, nullptr, islot, start, d);
        lvl_light<<<256 << d, NT, 0, stream>>>(Ubf, Fbf, biuo, Ufb, islot, cprev, cmine, h,
                                               start, d, cstart);
    }
}

// Round 7
// 1076.115 us; speedup vs baseline: 17.8972x; 1.0258x over previous
//
#include <hip/hip_runtime.h>

typedef float  f32x4  __attribute__((ext_vector_type(4)));
typedef short  s16x8  __attribute__((ext_vector_type(8)));
typedef short  s16x4  __attribute__((ext_vector_type(4)));
typedef _Float16 f16;

namespace {
constexpr int NN = 127, IDIM = 300, HD = 150;
constexpr int NT = 640, NW = 10;     // 10 waves; wave w owns cols 16w+l of each gate
constexpr int BCS  = 36;             // B-slab col stride (shorts): 18 dw -> 16-bank spread
constexpr int WSLAB = 17408;         // shorts (34 KiB; content 480*36=17280 + pad)
constexpr int WCH = 34;              // 1-KiB staging chunks per slab
constexpr int ASTR = 36;             // A-chunk row stride (shorts): 18 dw -> 16-bank spread
constexpr int A_SH = 64 * ASTR;      // 2304 shorts per A chunk buffer
constexpr int GEMM_LDS = (2 * A_SH + 2 * WSLAB) * 2;   // 78,848 B -> 2 blocks/CU
constexpr int CSTR = 164;            // light: chs stride (shorts)

constexpr int W_SH = 10 * WSLAB;     // W slabs (shorts)
constexpr int U_SH = 480 * 160;      // U plain [col][k]
constexpr int F_SH = 160 * 160;      // F plain [col][k]

// ws: c_all f16 [4096][126][150] (nodes 1..126) | iuo_all f16 [4096][63][456] | slabs
constexpr size_t C_N   = (size_t)4096 * 126 * HD;
constexpr size_t IUO_N = (size_t)4096 * 63 * 456;

__device__ __forceinline__ short f2bf(float f) {
    union { __bf16 b; short s; } u; u.b = (__bf16)f; return u.s;
}
__device__ __forceinline__ float bf2f(short s) {
    union { float f; unsigned u; } v; v.u = ((unsigned)(unsigned short)s) << 16; return v.f;
}
__device__ __forceinline__ float sig_(float x)  { return 1.0f / (1.0f + __expf(-x)); }
__device__ __forceinline__ float tanh_(float x) { float e = __expf(2.0f * x); return 1.0f - 2.0f / (e + 1.0f); }
__device__ __forceinline__ s16x4 cvt4(float a,float b,float c,float d) {
    return s16x4{ f2bf(a), f2bf(b), f2bf(c), f2bf(d) };
}
__device__ __forceinline__ s16x8 cat(s16x4 lo, s16x4 hi) {
    return __builtin_shufflevector(lo, hi, 0,1,2,3,4,5,6,7);
}
__device__ __forceinline__ f32x4 MFMA(s16x8 a, s16x8 b, f32x4 c) {
    return __builtin_amdgcn_mfma_f32_16x16x32_bf16(a, b, c, 0, 0, 0);
}

typedef const __attribute__((address_space(1))) unsigned int* gp_t;
typedef __attribute__((address_space(3))) unsigned int* lp_t;
__device__ __forceinline__ void stage_slab(const short* g, short* l, int nch, int wv, int ln) {
    const char* gb = (const char*)g;
    char* lb = (char*)l;
    for (int c = wv; c < nch; c += NW)
        __builtin_amdgcn_global_load_lds((gp_t)(gb + c * 1024 + ln * 16),
                                         (lp_t)(lb + c * 1024 + ln * 16), 16, 0, 0);
}
} // namespace

// -------- one-time weight prep: W -> K-chunk slabs [col][36]; U,F -> plain [col][160] --------
__global__ __launch_bounds__(256)
void prep_w(const float* __restrict__ Wiuo, const float* __restrict__ Uiuo,
            const float* __restrict__ Ufw, short* __restrict__ dst) {
    int i = blockIdx.x * 256 + threadIdx.x;
    short v = 0;
    if (i < W_SH) {
        int kc = i / WSLAB, r = i - kc * WSLAB;
        if (r < 480 * BCS) {
            int col = r / BCS, j = r - col * BCS;
            int g = col / 160, cp = col - g * 160, k = kc * 32 + j;
            if (cp < HD && j < 32 && k < IDIM) v = f2bf(Wiuo[(size_t)(g*HD + cp)*IDIM + k]);
        }
        dst[i] = v;
    } else if (i < W_SH + U_SH) {
        int q = i - W_SH;
        int col = q / 160, k = q - col * 160;
        int g = col / 160, cp = col - g * 160;
        if (cp < HD && k < HD) v = f2bf(Uiuo[(size_t)(g*HD + cp)*HD + k]);
        dst[i] = v;
    } else if (i < W_SH + U_SH + F_SH) {
        int q = i - W_SH - U_SH;
        int col = q / 160, k = q - col * 160;
        if (col < HD && k < HD) v = f2bf(Ufw[(size_t)col*HD + k]);
        dst[i] = v;
    }
}

// -------- merged projection GEMM over ALL levels (rows ordered level 6 first) --------
// Level d occupies rows [4096*(128-2^(d+1)), +4096*2^d). 2-phase pipeline: stage(k+1)
// issued at loop top (B via global_load_lds dbuf, A via reg-staged fp32->bf16 dbuf),
// one barrier per chunk. Leaf rows: fused gates; internal rows: iuo f16 (node-indexed).
// MFMA maps: A row=lane&15, B col=lane&15 (shared lane->k); C/D col=lane&15, row=4*(lane>>4)+reg.
__global__ __launch_bounds__(NT)
void big_gemm(const float* __restrict__ x, const short* __restrict__ Wsl,
              const float* __restrict__ biuo, float* __restrict__ h_all,
              f16* __restrict__ c_all, f16* __restrict__ iuo_all)
{
    extern __shared__ short smem[];
    short* A0 = smem;
    short* A1 = A0 + A_SH;
    short* B0 = A1 + A_SH;
    short* B1 = B0 + WSLAB;

    const int t = threadIdx.x;
    const int wv = t >> 6, ln = t & 63, l15 = ln & 15, kg = ln >> 4;
    const int row0 = blockIdx.x * 64;

    // block-uniform level detect (smallest d whose base <= row0; bases descend with d)
    int d = 6;
    for (int dd = 0; dd <= 5; ++dd)
        if (row0 >= 4096 * (128 - (2 << dd))) { d = dd; break; }
    const int base = 4096 * (128 - (2 << d));
    const int lg = d, mask = (1 << lg) - 1, start = (1 << lg) - 1;
    const int local0 = row0 - base;

    // staging duty: thread (row sr=t>>3, quad sq=t&7) loads x[row][kchunk*32 + sq*4 ..+3]
    const int sr = t >> 3, sq = t & 7;
    const float* xrow = nullptr;
    if (sr < 64) {
        int lcl = local0 + sr, b = lcl >> lg, s = lcl & mask;
        xrow = x + ((size_t)b * NN + start + s) * IDIM;
    }

    // prologue: slab 0 + A chunk 0
    stage_slab(Wsl, B0, WCH, wv, ln);
    if (sr < 64) {
        float4 f = *(const float4*)(xrow + sq * 4);    // chunk 0: k<32 all valid
        *(s16x4*)&A0[sr * ASTR + sq * 4] = cvt4(f.x, f.y, f.z, f.w);
    }
    __syncthreads();

    f32x4 acc[4][3] = {};
    #pragma unroll
    for (int kc = 0; kc < 10; ++kc) {
        short* Ac = (kc & 1) ? A1 : A0;
        short* An = (kc & 1) ? A0 : A1;
        short* Bc = (kc & 1) ? B1 : B0;
        short* Bn = (kc & 1) ? B0 : B1;
        // issue next-chunk staging first (lands during compute below)
        float4 nxt = {0.f, 0.f, 0.f, 0.f};
        if (kc < 9) {
            stage_slab(Wsl + (kc + 1) * WSLAB, Bn, WCH, wv, ln);
            if (sr < 64) {
                int k0 = (kc + 1) * 32 + sq * 4;
                if (k0 + 3 < IDIM) nxt = *(const float4*)(xrow + k0);
            }
        }
        // compute current chunk
        s16x8 a[4];
        #pragma unroll
        for (int mt = 0; mt < 4; ++mt) {
            const short* p = &Ac[(16*mt + l15) * ASTR + kg * 8];
            a[mt] = cat(*(const s16x4*)p, *(const s16x4*)(p + 4));
        }
        #pragma unroll
        for (int g = 0; g < 3; ++g) {
            const short* p = &Bc[(g*160 + 16*wv + l15) * BCS + kg * 8];
            s16x8 bf = cat(*(const s16x4*)p, *(const s16x4*)(p + 4));
            #pragma unroll
            for (int mt = 0; mt < 4; ++mt)
                acc[mt][g] = MFMA(a[mt], bf, acc[mt][g]);
        }
        if (kc < 9) {
            if (sr < 64)
                *(s16x4*)&An[sr * ASTR + sq * 4] = cvt4(nxt.x, nxt.y, nxt.z, nxt.w);
            __syncthreads();
        }
    }

    // epilogue
    const int c = 16 * wv + l15;
    if (c < HD) {
        if (d == 6) {
            float bi = biuo[c], bu = biuo[HD + c], bo = biuo[2*HD + c];
            #pragma unroll
            for (int mt = 0; mt < 4; ++mt)
                #pragma unroll
                for (int r = 0; r < 4; ++r) {
                    int lcl = local0 + 16*mt + 4*kg + r;
                    int b = lcl >> 6, s = lcl & 63;
                    float cn = sig_(acc[mt][0][r] + bi) * tanh_(acc[mt][1][r] + bu);
                    float hn = sig_(acc[mt][2][r] + bo) * tanh_(cn);
                    h_all[((size_t)b*NN + 63 + s) * HD + c] = hn;
                    c_all[((size_t)b*126 + 62 + s) * HD + c] = (f16)cn;
                }
        } else {
            #pragma unroll
            for (int mt = 0; mt < 4; ++mt)
                #pragma unroll
                for (int r = 0; r < 4; ++r) {
                    int lcl = local0 + 16*mt + 4*kg + r;
                    int b = lcl >> lg, s = lcl & mask;
                    f16* ip = iuo_all + ((size_t)b*63 + start + s) * 456;
                    ip[c]       = (f16)acc[mt][0][r];
                    ip[152 + c] = (f16)acc[mt][1][r];
                    ip[304 + c] = (f16)acc[mt][2][r];
                }
        }
    }
}

// -------- light: per internal level. 16 parents/block, 10 waves, 2 barriers --------
__global__ __launch_bounds__(NT, 5)
void lvl_light(const short* __restrict__ Ubf, const short* __restrict__ Fbf,
               const float* __restrict__ biuo, const float* __restrict__ Ufb,
               const f16* __restrict__ iuo_all, f16* __restrict__ c_all,
               float* __restrict__ h_all, int start, int lg, int cstart)
{
    __shared__ short chs[2][16][CSTR];   // [child][parent][k] bf16
    __shared__ short fgs[NW][32][16];    // per-wave f-gates

    const int t = threadIdx.x;
    const int wv = t >> 6, ln = t & 63, l15 = ln & 15, kg = ln >> 4;
    const int row0 = blockIdx.x * 16;
    const int mask = (1 << lg) - 1;
    const int c = wv * 16 + l15;     // padded col 0..159

    // stage children h (fp32 -> bf16 LDS)
    {
        int rc = t & 31, part = t >> 5;          // part 0..19 covers k [0,160)
        int plane = rc >> 4, lr = rc & 15;
        int row = row0 + lr, b = row >> lg, s = row & mask;
        const float* hp = h_all + ((size_t)b*NN + cstart + 2*s + plane) * HD;
        short* dst = &chs[plane][lr][part * 8];
        if (part < 18) {
            float4 f0 = *(const float4*)(hp + part*8);
            float4 f1 = *(const float4*)(hp + part*8 + 4);
            *(s16x4*)dst       = cvt4(f0.x, f0.y, f0.z, f0.w);
            *(s16x4*)(dst + 4) = cvt4(f1.x, f1.y, f1.z, f1.w);
        } else if (part == 18) {
            float4 f0 = *(const float4*)(hp + 144);
            float2 f1 = *(const float2*)(hp + 148);
            *(s16x4*)dst       = cvt4(f0.x, f0.y, f0.z, f0.w);
            *(s16x4*)(dst + 4) = s16x4{ f2bf(f1.x), f2bf(f1.y), 0, 0 };
        } else {
            *(s16x4*)dst = s16x4{0,0,0,0};
            *(s16x4*)(dst + 4) = s16x4{0,0,0,0};
        }
    }
    __syncthreads();

    // F phase: f = sigmoid(ch @ F^T + b) for this wave's 16 cols
    f32x4 facc[2] = {};
    #pragma unroll
    for (int kc = 0; kc < 5; ++kc) {
        int ka = kc * 32 + kg * 8;
        s16x8 bf = *(const s16x8*)(Fbf + (size_t)c * 160 + ka);
        #pragma unroll
        for (int rt = 0; rt < 2; ++rt) {
            const short* p = &chs[rt][l15][ka];
            s16x8 af = cat(*(const s16x4*)p, *(const s16x4*)(p + 4));
            facc[rt] = MFMA(af, bf, facc[rt]);
        }
    }
    {
        float fb_ = (c < HD) ? Ufb[c] : 0.0f;
        #pragma unroll
        for (int rt = 0; rt < 2; ++rt)
            #pragma unroll
            for (int r = 0; r < 4; ++r)
                fgs[wv][rt*16 + 4*kg + r][l15] = f2bf(sig_(facc[rt][r] + fb_));
    }
    __syncthreads();

    // U phase: acc = h_tilda @ U^T
    f32x4 acc[3] = {};
    #pragma unroll
    for (int kc = 0; kc < 5; ++kc) {
        int ka = kc * 32 + kg * 8;
        const short* p0 = &chs[0][l15][ka];
        const short* p1 = &chs[1][l15][ka];
        s16x8 h0 = cat(*(const s16x4*)p0, *(const s16x4*)(p0 + 4));
        s16x8 h1 = cat(*(const s16x4*)p1, *(const s16x4*)(p1 + 4));
        s16x8 hs;
        #pragma unroll
        for (int e = 0; e < 8; ++e)
            hs[e] = f2bf(bf2f(h0[e]) + bf2f(h1[e]));
        #pragma unroll
        for (int g = 0; g < 3; ++g) {
            s16x8 bf = *(const s16x8*)(Ubf + (size_t)(g*160 + c) * 160 + ka);
            acc[g] = MFMA(hs, bf, acc[g]);
        }
    }

    // epilogue
    if (c < HD) {
        float bi = biuo[c], bu = biuo[HD + c], bo = biuo[2*HD + c];
        #pragma unroll
        for (int r = 0; r < 4; ++r) {
            int pl = 4*kg + r;
            int row = row0 + pl, b = row >> lg, s = row & mask;
            const f16* ip = iuo_all + ((size_t)b*63 + start + s) * 456;
            float ig = (float)ip[c]       + bi + acc[0][r];
            float ug = (float)ip[152 + c] + bu + acc[1][r];
            float og = (float)ip[304 + c] + bo + acc[2][r];
            float f0 = bf2f(fgs[wv][pl][l15]);
            float f1 = bf2f(fgs[wv][16 + pl][l15]);
            size_t ci = (size_t)b*126 + (cstart + 2*s - 1);
            float c0 = (float)c_all[ci * HD + c];
            float c1 = (float)c_all[(ci + 1) * HD + c];
            float cn = sig_(ig) * tanh_(ug) + f0*c0 + f1*c1;
            float hn = sig_(og) * tanh_(cn);
            h_all[((size_t)b*NN + start + s) * HD + c] = hn;
            if (start > 0)   // root c never read
                c_all[((size_t)b*126 + start + s - 1) * HD + c] = (f16)cn;
        }
    }
}

extern "C" void kernel_launch(void* const* d_in, const int* in_sizes, int n_in,
                              void* d_out, int out_size, void* d_ws, size_t ws_size,
                              hipStream_t stream) {
    const float* x    = (const float*)d_in[0];
    const float* Wiuo = (const float*)d_in[1];
    const float* Uiuo = (const float*)d_in[2];
    const float* biuo = (const float*)d_in[3];
    const float* Ufw  = (const float*)d_in[4];
    const float* Ufb  = (const float*)d_in[5];
    float* h = (float*)d_out;

    f16* c_all   = (f16*)d_ws;                 // 155 MB
    f16* iuo_all = c_all + C_N;                // 236 MB
    short* slabs = (short*)(iuo_all + IUO_N);  // 0.55 MB
    const short* Wsl = slabs;
    const short* Ubf = slabs + W_SH;
    const short* Fbf = slabs + W_SH + U_SH;

    (void)hipFuncSetAttribute((const void*)big_gemm,
                              hipFuncAttributeMaxDynamicSharedMemorySize, 160 * 1024);

    prep_w<<<(W_SH + U_SH + F_SH + 255) / 256, 256, 0, stream>>>(Wiuo, Uiuo, Ufw, slabs);

    // all projections + leaf gates in one launch
    big_gemm<<<8128, NT, GEMM_LDS, stream>>>(x, Wsl, biuo, h, c_all, iuo_all);

    // recurrent chain
    for (int d = 5; d >= 0; --d) {
        const int start = (1 << d) - 1, cstart = (1 << (d+1)) - 1;
        lvl_light<<<256 << d, NT, 0, stream>>>(Ubf, Fbf, biuo, Ufb, iuo_all, c_all, h,
                                               start, d, cstart);
    }
}